// Round 1
// baseline (326.521 us; speedup 1.0000x reference)
//
#include <hip/hip_runtime.h>

#define HH 2160
#define WW 3840
#define K 31
#define RAD 15
#define TW 64
#define TH 16
#define IW (TW + K - 1)   // 94
#define IH (TH + K - 1)   // 46
#define IWP 96            // padded LDS row
#define NTHREADS 256
#define PPT ((TW * TH) / NTHREADS)  // 4 pixels per thread

__global__ __launch_bounds__(NTHREADS) void blur_masked_kernel(
    const float* __restrict__ img, const float* __restrict__ mask,
    const float* __restrict__ kern, float* __restrict__ out)
{
    __shared__ float s_in[IH][IWP];
    __shared__ float s_tmp[IH][TW];
    __shared__ float s_k1[K];

    const int tilesX = WW / TW;            // 60
    const int tx = blockIdx.x % tilesX;
    const int ty = blockIdx.x / tilesX;
    const int x0 = tx * TW;
    const int y0 = ty * TH;
    const int t  = threadIdx.x;

    // ---- load mask for this block's output pixels; block-uniform skip test ----
    float mval[PPT];
    int anyLocal = 0;
    #pragma unroll
    for (int p = 0; p < PPT; ++p) {
        int idx = t + p * NTHREADS;
        int r = idx / TW, c = idx % TW;
        float m = mask[(size_t)(y0 + r) * WW + (x0 + c)];
        mval[p] = m;
        anyLocal |= (m != 0.0f);
    }
    int any = __syncthreads_or(anyLocal);

    if (!any) {
        // pure copy: out = img * 255 (mask==0 everywhere in tile)
        #pragma unroll
        for (int p = 0; p < PPT; ++p) {
            int idx = t + p * NTHREADS;
            int r = idx / TW, c = idx % TW;
            int gy = y0 + r, gx = x0 + c;
            size_t pix = (size_t)gy * WW + gx;
            size_t obase = pix * 3;
            #pragma unroll
            for (int ch = 0; ch < 3; ++ch) {
                out[obase + ch] = img[(size_t)ch * HH * WW + pix] * 255.0f;
            }
        }
        return;
    }

    // ---- blur path ----
    float acc[3][PPT];

    for (int ch = 0; ch < 3; ++ch) {
        __syncthreads();  // protect LDS reuse across channel iterations

        // k1[i] = row-sum of the 2D kernel (== k1 since sum(k1)≈1)
        if (t < K) {
            float s = 0.f;
            const float* kr = kern + ch * K * K + t * K;
            #pragma unroll
            for (int j = 0; j < K; ++j) s += kr[j];
            s_k1[t] = s;
        }

        // stage halo tile (zero-padded SAME boundary)
        const float* imc = img + (size_t)ch * HH * WW;
        for (int i = t; i < IH * IW; i += NTHREADS) {
            int r = i / IW, c = i % IW;
            int gy = y0 - RAD + r, gx = x0 - RAD + c;
            float v = 0.f;
            if (gy >= 0 && gy < HH && gx >= 0 && gx < WW)
                v = imc[(size_t)gy * WW + gx];
            s_in[r][c] = v;
        }
        __syncthreads();

        // horizontal pass: IH x TW
        for (int i = t; i < IH * TW; i += NTHREADS) {
            int r = i / TW, c = i % TW;
            float s = 0.f;
            #pragma unroll
            for (int j = 0; j < K; ++j)
                s += s_in[r][c + j] * s_k1[j];
            s_tmp[r][c] = s;
        }
        __syncthreads();

        // vertical pass into registers
        #pragma unroll
        for (int p = 0; p < PPT; ++p) {
            int idx = t + p * NTHREADS;
            int r = idx / TW, c = idx % TW;
            float s = 0.f;
            #pragma unroll
            for (int i = 0; i < K; ++i)
                s += s_tmp[r + i][c] * s_k1[i];
            acc[ch][p] = s;
        }
    }

    // ---- blend + HWC write, x255 ----
    #pragma unroll
    for (int p = 0; p < PPT; ++p) {
        int idx = t + p * NTHREADS;
        int r = idx / TW, c = idx % TW;
        int gy = y0 + r, gx = x0 + c;
        size_t pix = (size_t)gy * WW + gx;
        float m = mval[p];
        float om = 1.0f - m;
        size_t obase = pix * 3;
        #pragma unroll
        for (int ch = 0; ch < 3; ++ch) {
            float iv = img[(size_t)ch * HH * WW + pix];
            out[obase + ch] = (iv * om + acc[ch][p] * m) * 255.0f;
        }
    }
}

extern "C" void kernel_launch(void* const* d_in, const int* in_sizes, int n_in,
                              void* d_out, int out_size, void* d_ws, size_t ws_size,
                              hipStream_t stream) {
    const float* img  = (const float*)d_in[0];
    const float* mask = (const float*)d_in[1];
    const float* kern = (const float*)d_in[2];
    float* out = (float*)d_out;
    int nblocks = (WW / TW) * (HH / TH);  // 60 * 135 = 8100
    blur_masked_kernel<<<nblocks, NTHREADS, 0, stream>>>(img, mask, kern, out);
}

// Round 2
// 115.635 us; speedup vs baseline: 2.8237x; 2.8237x over previous
//
#include <hip/hip_runtime.h>

#define HH 2160
#define WW 3840
#define K 31
#define RAD 15
#define TW 64
#define TH 16
#define IW 96             // staged cols: gx in [x0-16, x0+80), 16B-aligned
#define IH (TH + K - 1)   // 46
#define NTHREADS 256
#define PPT 4             // pixels per thread (rows r0..r0+3 of one column)

__global__ __launch_bounds__(NTHREADS, 4) void blur_masked_kernel(
    const float* __restrict__ img, const float* __restrict__ mask,
    const float* __restrict__ kern, float* __restrict__ out)
{
    __shared__ float s_in[IH][IW];    // halo tile, one channel at a time
    __shared__ float s_tmp[IH][TW];   // horizontal-pass output
    __shared__ float s_k1[K];

    const int tilesX = WW / TW;            // 60
    const int tx = blockIdx.x % tilesX;
    const int ty = blockIdx.x / tilesX;
    const int x0 = tx * TW;
    const int y0 = ty * TH;
    const int t  = threadIdx.x;

    // thread -> output pixels: column c, rows r0..r0+3
    const int c  = t & 63;
    const int r0 = (t >> 6) * PPT;

    // ---- 1D kernel = row sums of 2D kernel (kernel identical per channel) ----
    if (t < K) {
        float s = 0.f;
        const float* kr = kern + t * K;
        #pragma unroll
        for (int j = 0; j < K; ++j) s += kr[j];
        s_k1[t] = s;
    }

    // ---- mask for this thread's 4 pixels; block-uniform skip test ----
    float mval[PPT];
    int anyLocal = 0;
    #pragma unroll
    for (int p = 0; p < PPT; ++p) {
        mval[p] = mask[(size_t)(y0 + r0 + p) * WW + (x0 + c)];
        anyLocal |= (mval[p] != 0.0f);
    }
    int any = __syncthreads_or(anyLocal);   // also publishes s_k1

    if (!any) {
        // pure copy: out = img * 255
        #pragma unroll
        for (int p = 0; p < PPT; ++p) {
            size_t pix = (size_t)(y0 + r0 + p) * WW + (x0 + c);
            size_t obase = pix * 3;
            #pragma unroll
            for (int ch = 0; ch < 3; ++ch)
                out[obase + ch] = img[(size_t)ch * HH * WW + pix] * 255.0f;
        }
        return;
    }

    // hoist 1D taps into registers (broadcast LDS reads, once)
    float k1[K];
    #pragma unroll
    for (int j = 0; j < K; ++j) k1[j] = s_k1[j];

    // H-pass thread mapping: 4 consecutive cols, one row, 3 row-iterations
    const int hc0 = (t & 15) * 4;   // 0,4,...,60
    const int hr  = t >> 4;         // 0..15

    for (int ch = 0; ch < 3; ++ch) {
        __syncthreads();  // s_in reuse guard (vs previous channel's blend reads)

        // ---- stage halo tile: 46 rows x 24 float4 (16B-aligned both sides) ----
        const float* imc = img + (size_t)ch * HH * WW;
        for (int i = t; i < IH * (IW / 4); i += NTHREADS) {
            int r  = i / (IW / 4);
            int c4 = i % (IW / 4);
            int gy = y0 - RAD + r;
            int gx = x0 - 16 + c4 * 4;     // each float4 fully in or out in x
            float4 v = make_float4(0.f, 0.f, 0.f, 0.f);
            if (gy >= 0 && gy < HH && gx >= 0 && gx < WW)
                v = *(const float4*)(imc + (size_t)gy * WW + gx);
            *(float4*)&s_in[r][c4 * 4] = v;
        }
        __syncthreads();

        // ---- horizontal pass: sliding window, 4 outputs/thread/iter ----
        #pragma unroll
        for (int it = 0; it < 3; ++it) {
            int r = hr + 16 * it;
            if (r < IH) {
                float a0 = 0.f, a1 = 0.f, a2 = 0.f, a3 = 0.f;
                const float* row = &s_in[r][hc0];
                #pragma unroll
                for (int q = 0; q < 9; ++q) {
                    float4 w = *(const float4*)(row + 4 * q);
                    #pragma unroll
                    for (int e = 0; e < 4; ++e) {
                        const int idx = 4 * q + e;          // 0..35
                        float v = (e == 0) ? w.x : (e == 1) ? w.y : (e == 2) ? w.z : w.w;
                        // output j uses s_in col hc0 + 1 + j + i, i in [0,30]
                        if (idx - 1 >= 0 && idx - 1 <= 30) a0 += v * k1[idx - 1];
                        if (idx - 2 >= 0 && idx - 2 <= 30) a1 += v * k1[idx - 2];
                        if (idx - 3 >= 0 && idx - 3 <= 30) a2 += v * k1[idx - 3];
                        if (idx - 4 >= 0 && idx - 4 <= 30) a3 += v * k1[idx - 4];
                    }
                }
                *(float4*)&s_tmp[r][hc0] = make_float4(a0, a1, a2, a3);
            }
        }
        __syncthreads();

        // ---- vertical pass: stream 34 rows, 4 outputs/thread ----
        float b0 = 0.f, b1 = 0.f, b2 = 0.f, b3 = 0.f;
        #pragma unroll
        for (int i = 0; i < 34; ++i) {
            float v = s_tmp[r0 + i][c];
            if (i - 0 >= 0 && i - 0 <= 30) b0 += v * k1[i - 0];
            if (i - 1 >= 0 && i - 1 <= 30) b1 += v * k1[i - 1];
            if (i - 2 >= 0 && i - 2 <= 30) b2 += v * k1[i - 2];
            if (i - 3 >= 0 && i - 3 <= 30) b3 += v * k1[i - 3];
        }

        // ---- blend + write this channel (img value read from staged LDS) ----
        float bl[PPT] = {b0, b1, b2, b3};
        #pragma unroll
        for (int p = 0; p < PPT; ++p) {
            float iv = s_in[r0 + p + RAD][c + 16];
            float m  = mval[p];
            size_t pix = (size_t)(y0 + r0 + p) * WW + (x0 + c);
            out[pix * 3 + ch] = (iv * (1.0f - m) + bl[p] * m) * 255.0f;
        }
    }
}

extern "C" void kernel_launch(void* const* d_in, const int* in_sizes, int n_in,
                              void* d_out, int out_size, void* d_ws, size_t ws_size,
                              hipStream_t stream) {
    const float* img  = (const float*)d_in[0];
    const float* mask = (const float*)d_in[1];
    const float* kern = (const float*)d_in[2];
    float* out = (float*)d_out;
    int nblocks = (WW / TW) * (HH / TH);  // 60 * 135 = 8100
    blur_masked_kernel<<<nblocks, NTHREADS, 0, stream>>>(img, mask, kern, out);
}

// Round 3
// 109.446 us; speedup vs baseline: 2.9834x; 1.0565x over previous
//
#include <hip/hip_runtime.h>

#define HH 2160
#define WW 3840
#define K 31
#define RAD 15
#define TW 64
#define TH 16
#define IW 96             // staged cols: gx in [x0-16, x0+80)
#define IH 46             // TH + K - 1
#define NTHREADS 256
#define NF4 (IH * (IW/4))  // 1104 float4 to stage
#define NROUND 5           // 5 full rounds of 256 (pad to 1280)

#define GLDS(gp, lp) __builtin_amdgcn_global_load_lds(                         \
    (const __attribute__((address_space(1))) void*)(gp),                       \
    (__attribute__((address_space(3))) void*)(lp), 16, 0, 0)

__device__ __forceinline__ float fcomp(float4 v, int p) {
    switch (p) { case 0: return v.x; case 1: return v.y; case 2: return v.z; default: return v.w; }
}

__global__ __launch_bounds__(NTHREADS, 5) void blur_masked_kernel(
    const float* __restrict__ img, const float* __restrict__ mask,
    const float* __restrict__ kern, float* __restrict__ out)
{
    __shared__ float s_in[NROUND * NTHREADS * 4];  // 1280 float4 = 20 KB (incl pad)
    __shared__ float s_tmp[TH * IW];               // 6 KB
    __shared__ float s_k1[K];

    const int tilesX = WW / TW;            // 60
    const int tx = blockIdx.x % tilesX;
    const int ty = blockIdx.x / tilesX;
    const int x0 = tx * TW;
    const int y0 = ty * TH;
    const int t  = threadIdx.x;

    // unified thread -> pixel mapping: row hr, 4 consecutive cols hc0..hc0+3
    const int hr  = t >> 4;         // 0..15
    const int hc0 = (t & 15) * 4;   // 0,4,...,60

    // ---- 1D kernel = row sums of 2D kernel (identical per channel) ----
    if (t < K) {
        float s = 0.f;
        const float* kr = kern + t * K;
        #pragma unroll
        for (int j = 0; j < K; ++j) s += kr[j];
        s_k1[t] = s;
    }

    // ---- mask for this thread's 4 pixels (aligned float4) ----
    const size_t pix0 = (size_t)(y0 + hr) * WW + (x0 + hc0);
    float4 mv = *(const float4*)(mask + pix0);
    int anyLocal = (mv.x != 0.f) | (mv.y != 0.f) | (mv.z != 0.f) | (mv.w != 0.f);
    int any = __syncthreads_or(anyLocal);   // also publishes s_k1

    if (!any) {
        // pure copy: out = img * 255, fully vectorized, interleave in regs
        const size_t HW = (size_t)HH * WW;
        float4 i0 = *(const float4*)(img + pix0);
        float4 i1 = *(const float4*)(img + HW + pix0);
        float4 i2 = *(const float4*)(img + 2 * HW + pix0);
        float* ob = out + pix0 * 3;
        float4 w0 = make_float4(i0.x, i1.x, i2.x, i0.y);
        float4 w1 = make_float4(i1.y, i2.y, i0.z, i1.z);
        float4 w2 = make_float4(i2.z, i0.w, i1.w, i2.w);
        w0.x *= 255.f; w0.y *= 255.f; w0.z *= 255.f; w0.w *= 255.f;
        w1.x *= 255.f; w1.y *= 255.f; w1.z *= 255.f; w1.w *= 255.f;
        w2.x *= 255.f; w2.y *= 255.f; w2.z *= 255.f; w2.w *= 255.f;
        *(float4*)(ob)     = w0;
        *(float4*)(ob + 4) = w1;
        *(float4*)(ob + 8) = w2;
        return;
    }

    // hoist taps into registers
    float k1r[K];
    #pragma unroll
    for (int j = 0; j < K; ++j) k1r[j] = s_k1[j];

    // interior tile: whole halo (incl. pad rows, clamped) in-bounds
    const bool interior = (tx >= 1) && (tx <= 58) && (ty >= 1) && (ty <= 133);

    auto stage = [&](int ch) {
        const float* imc = img + (size_t)ch * HH * WW;
        if (interior) {
            #pragma unroll
            for (int k2 = 0; k2 < NROUND; ++k2) {
                int i = t + k2 * NTHREADS;            // 0..1279
                int r = i / (IW / 4), c4 = i % (IW / 4);
                int gy = y0 - RAD + r;
                if (gy > HH - 1) gy = HH - 1;         // pad rows -> clamp (junk, unused)
                const float* gp = imc + (size_t)gy * WW + (x0 - 16 + 4 * c4);
                GLDS(gp, s_in + 4 * i);
            }
        } else {
            #pragma unroll
            for (int k2 = 0; k2 < NROUND; ++k2) {
                int i = t + k2 * NTHREADS;
                int r = i / (IW / 4), c4 = i % (IW / 4);
                int gy = y0 - RAD + r, gx = x0 - 16 + 4 * c4;
                float4 v = make_float4(0.f, 0.f, 0.f, 0.f);
                if (r < IH && gy >= 0 && gy < HH && gx >= 0 && gx < WW)
                    v = *(const float4*)(imc + (size_t)gy * WW + gx);
                *(float4*)(s_in + 4 * i) = v;
            }
        }
    };

    stage(0);

    float acc[3][4];
    float4 iv[3];

    #pragma unroll
    for (int ch = 0; ch < 3; ++ch) {
        __syncthreads();   // staging(ch) done; prev H-pass s_tmp reads done

        // ---- vertical pass first: s_in[46][96] -> s_tmp[16][96] ----
        #pragma unroll
        for (int k2 = 0; k2 < 6; ++k2) {
            int i = t + k2 * NTHREADS;   // 0..1535
            int r = i / IW, cc = i % IW;
            float s = 0.f;
            #pragma unroll
            for (int j = 0; j < K; ++j)
                s += s_in[(r + j) * IW + cc] * k1r[j];
            s_tmp[r * IW + cc] = s;
        }
        // capture img values for blend while s_in is live (aligned float4)
        iv[ch] = *(const float4*)(s_in + (hr + RAD) * IW + hc0 + 16);

        __syncthreads();   // s_tmp ready; s_in free

        if (ch < 2) stage(ch + 1);   // HBM latency hides under H-pass

        // ---- horizontal pass: sliding window, 4 outputs/thread ----
        float a0 = 0.f, a1 = 0.f, a2 = 0.f, a3 = 0.f;
        const float* rowp = s_tmp + hr * IW + hc0;
        #pragma unroll
        for (int q = 0; q < 9; ++q) {
            float4 w = *(const float4*)(rowp + 4 * q);
            #pragma unroll
            for (int e = 0; e < 4; ++e) {
                const int idx = 4 * q + e;   // window col offset 0..35
                float v = fcomp(w, e);
                if (idx - 1 >= 0 && idx - 1 <= 30) a0 += v * k1r[idx - 1];
                if (idx - 2 >= 0 && idx - 2 <= 30) a1 += v * k1r[idx - 2];
                if (idx - 3 >= 0 && idx - 3 <= 30) a2 += v * k1r[idx - 3];
                if (idx - 4 >= 0 && idx - 4 <= 30) a3 += v * k1r[idx - 4];
            }
        }
        acc[ch][0] = a0; acc[ch][1] = a1; acc[ch][2] = a2; acc[ch][3] = a3;
    }

    // ---- blend + interleaved HWC write: 3 aligned float4 per thread ----
    float o[12];
    #pragma unroll
    for (int p = 0; p < 4; ++p) {
        float m = fcomp(mv, p), om = 1.f - m;
        #pragma unroll
        for (int ch = 0; ch < 3; ++ch)
            o[p * 3 + ch] = (fcomp(iv[ch], p) * om + acc[ch][p] * m) * 255.f;
    }
    float* ob = out + pix0 * 3;
    *(float4*)(ob)     = make_float4(o[0], o[1], o[2],  o[3]);
    *(float4*)(ob + 4) = make_float4(o[4], o[5], o[6],  o[7]);
    *(float4*)(ob + 8) = make_float4(o[8], o[9], o[10], o[11]);
}

extern "C" void kernel_launch(void* const* d_in, const int* in_sizes, int n_in,
                              void* d_out, int out_size, void* d_ws, size_t ws_size,
                              hipStream_t stream) {
    const float* img  = (const float*)d_in[0];
    const float* mask = (const float*)d_in[1];
    const float* kern = (const float*)d_in[2];
    float* out = (float*)d_out;
    int nblocks = (WW / TW) * (HH / TH);  // 8100
    blur_masked_kernel<<<nblocks, NTHREADS, 0, stream>>>(img, mask, kern, out);
}

// Round 4
// 59.044 us; speedup vs baseline: 5.5301x; 1.8536x over previous
//
#include <hip/hip_runtime.h>

#define HH 2160
#define WW 3840
#define K 31
#define RAD 15
#define TW 64
#define TH 16
#define IW 96             // staged cols: gx in [x0-16, x0+80)
#define IH 46             // TH + K - 1
#define NTHREADS 256
#define NROUND 5          // 5 rounds of 256 float4 (pad to 1280)
#define TMPW 100          // padded s_tmp row stride

#define GLDS(gp, lp) __builtin_amdgcn_global_load_lds(                         \
    (const __attribute__((address_space(1))) void*)(gp),                       \
    (__attribute__((address_space(3))) void*)(lp), 16, 0, 0)

__device__ __forceinline__ float fcomp(float4 v, int p) {
    switch (p) { case 0: return v.x; case 1: return v.y; case 2: return v.z; default: return v.w; }
}

__device__ __forceinline__ float uniformf(float x) {
    return __uint_as_float(__builtin_amdgcn_readfirstlane(__float_as_uint(x)));
}

__global__ __launch_bounds__(NTHREADS, 4) void blur_masked_kernel(
    const float* __restrict__ img, const float* __restrict__ mask,
    const float* __restrict__ kern, float* __restrict__ out)
{
    __shared__ float s_in[NROUND * NTHREADS * 4];  // 5120 floats = 20 KB
    __shared__ float s_tmp[TH * TMPW];             // 6.25 KB
    __shared__ float s_k1[K];

    const int tilesX = WW / TW;            // 60
    const int tx = blockIdx.x % tilesX;
    const int ty = blockIdx.x / tilesX;
    const int x0 = tx * TW;
    const int y0 = ty * TH;
    const int t  = threadIdx.x;

    // unified thread -> pixel mapping: row hr, 4 consecutive cols hc0..hc0+3
    const int hr  = t >> 4;         // 0..15
    const int hc0 = (t & 15) * 4;   // 0,4,...,60

    // ---- 1D kernel = row sums of 2D kernel (identical per channel) ----
    if (t < K) {
        float s = 0.f;
        const float* kr = kern + t * K;
        #pragma unroll
        for (int j = 0; j < K; ++j) s += kr[j];
        s_k1[t] = s;
    }

    // ---- mask for this thread's 4 pixels (aligned float4) ----
    const size_t pix0 = (size_t)(y0 + hr) * WW + (x0 + hc0);
    float4 mv = *(const float4*)(mask + pix0);
    int anyLocal = (mv.x != 0.f) | (mv.y != 0.f) | (mv.z != 0.f) | (mv.w != 0.f);
    int any = __syncthreads_or(anyLocal);   // also publishes s_k1

    if (!any) {
        // pure copy: out = img * 255, fully vectorized, interleave in regs
        const size_t HW = (size_t)HH * WW;
        float4 i0 = *(const float4*)(img + pix0);
        float4 i1 = *(const float4*)(img + HW + pix0);
        float4 i2 = *(const float4*)(img + 2 * HW + pix0);
        float* ob = out + pix0 * 3;
        *(float4*)(ob)     = make_float4(i0.x * 255.f, i1.x * 255.f, i2.x * 255.f, i0.y * 255.f);
        *(float4*)(ob + 4) = make_float4(i1.y * 255.f, i2.y * 255.f, i0.z * 255.f, i1.z * 255.f);
        *(float4*)(ob + 8) = make_float4(i2.z * 255.f, i0.w * 255.f, i1.w * 255.f, i2.w * 255.f);
        return;
    }

    // taps -> SGPRs (wave-uniform; v_fmac_f32 takes one SGPR src)
    float k1r[K];
    #pragma unroll
    for (int j = 0; j < K; ++j) k1r[j] = uniformf(s_k1[j]);

    // interior tile: whole halo (pad rows clamped) in-bounds
    const bool interior = (tx >= 1) && (tx <= 58) && (ty >= 1) && (ty <= 133);

    auto stage = [&](int ch) {
        const float* imc = img + (size_t)ch * HH * WW;
        if (interior) {
            #pragma unroll
            for (int k2 = 0; k2 < NROUND; ++k2) {
                int i = t + k2 * NTHREADS;            // 0..1279
                int r = i / (IW / 4), c4 = i % (IW / 4);
                int gy = y0 - RAD + r;
                if (gy > HH - 1) gy = HH - 1;         // pad rows -> clamp (junk, unused)
                const float* gp = imc + (size_t)gy * WW + (x0 - 16 + 4 * c4);
                GLDS(gp, s_in + 4 * i);
            }
        } else {
            #pragma unroll
            for (int k2 = 0; k2 < NROUND; ++k2) {
                int i = t + k2 * NTHREADS;
                int r = i / (IW / 4), c4 = i % (IW / 4);
                int gy = y0 - RAD + r, gx = x0 - 16 + 4 * c4;
                float4 v = make_float4(0.f, 0.f, 0.f, 0.f);
                if (r < IH && gy >= 0 && gy < HH && gx >= 0 && gx < WW)
                    v = *(const float4*)(imc + (size_t)gy * WW + gx);
                *(float4*)(s_in + 4 * i) = v;
            }
        }
    };

    stage(0);

    float o[12];   // final interleaved pixels, built incrementally per channel

    #pragma unroll
    for (int ch = 0; ch < 3; ++ch) {
        __syncthreads();   // staging(ch) done (drains vmcnt); prev H-pass s_tmp reads done

        // ---- vertical pass: paired rows (r, r+8) share 23/39 window reads ----
        #pragma unroll
        for (int k2 = 0; k2 < 3; ++k2) {
            int i = t + k2 * NTHREADS;       // 0..767
            int r = i / IW, cc = i % IW;     // r in [0,8)
            float a0 = 0.f, a1 = 0.f;
            #pragma unroll
            for (int u = 0; u < 39; ++u) {
                float v = s_in[(r + u) * IW + cc];
                if (u <= 30) a0 += v * k1r[u];
                if (u >= 8)  a1 += v * k1r[u - 8];
            }
            s_tmp[r * TMPW + cc]       = a0;
            s_tmp[(r + 8) * TMPW + cc] = a1;
        }
        // capture img values for blend while s_in is live (aligned float4)
        float4 iv = *(const float4*)(s_in + (hr + RAD) * IW + hc0 + 16);

        __syncthreads();   // s_tmp ready; s_in free

        if (ch < 2) stage(ch + 1);   // HBM latency hides under H-pass

        // ---- horizontal pass: sliding window, 4 outputs/thread ----
        float a0 = 0.f, a1 = 0.f, a2 = 0.f, a3 = 0.f;
        const float* rowp = s_tmp + hr * TMPW + hc0;
        #pragma unroll
        for (int q = 0; q < 9; ++q) {
            float4 w = *(const float4*)(rowp + 4 * q);
            #pragma unroll
            for (int e = 0; e < 4; ++e) {
                const int idx = 4 * q + e;   // window col offset 0..35
                float v = fcomp(w, e);
                if (idx - 1 >= 0 && idx - 1 <= 30) a0 += v * k1r[idx - 1];
                if (idx - 2 >= 0 && idx - 2 <= 30) a1 += v * k1r[idx - 2];
                if (idx - 3 >= 0 && idx - 3 <= 30) a2 += v * k1r[idx - 3];
                if (idx - 4 >= 0 && idx - 4 <= 30) a3 += v * k1r[idx - 4];
            }
        }

        // ---- blend this channel into the interleaved output registers ----
        float bl[4] = {a0, a1, a2, a3};
        #pragma unroll
        for (int p = 0; p < 4; ++p) {
            float m = fcomp(mv, p);
            o[p * 3 + ch] = (fcomp(iv, p) * (1.f - m) + bl[p] * m) * 255.f;
        }
    }

    // ---- 3 aligned float4 stores (full-line coalesced) ----
    float* ob = out + pix0 * 3;
    *(float4*)(ob)     = make_float4(o[0], o[1], o[2],  o[3]);
    *(float4*)(ob + 4) = make_float4(o[4], o[5], o[6],  o[7]);
    *(float4*)(ob + 8) = make_float4(o[8], o[9], o[10], o[11]);
}

extern "C" void kernel_launch(void* const* d_in, const int* in_sizes, int n_in,
                              void* d_out, int out_size, void* d_ws, size_t ws_size,
                              hipStream_t stream) {
    const float* img  = (const float*)d_in[0];
    const float* mask = (const float*)d_in[1];
    const float* kern = (const float*)d_in[2];
    float* out = (float*)d_out;
    int nblocks = (WW / TW) * (HH / TH);  // 8100
    blur_masked_kernel<<<nblocks, NTHREADS, 0, stream>>>(img, mask, kern, out);
}